// Round 1
// baseline (811.267 us; speedup 1.0000x reference)
//
#include <hip/hip_runtime.h>

#define NN 16384          // sequence length
#define NB 8              // batch
#define NC 16             // layer channels
#define NPOSTOT (NB * NN) // total positions = 131072

typedef float4 f4;

// ---------------- layer 0: causal conv 1->16, d=1, plus broadcast residual ----
__global__ __launch_bounds__(256) void layer0_k(
    const float* __restrict__ x,
    const float* __restrict__ W0, const float* __restrict__ b0,
    float* __restrict__ dst)
{
    const int p = blockIdx.x * 256 + threadIdx.x;     // position in [0, B*N)
    const int n = p & (NN - 1);
    const float xs = x[p] * (1.0f / 32768.0f);
    const float xm = (n >= 1) ? x[p - 1] * (1.0f / 32768.0f) : 0.0f;

    float v[NC];
#pragma unroll
    for (int c = 0; c < NC; ++c) {
        // h = W0[c][0][0]*x[n-1] + W0[c][0][1]*x[n] + b0[c]; inp = xs + h
        v[c] = xs + fmaf(W0[c * 2], xm, fmaf(W0[c * 2 + 1], xs, b0[c]));
    }
    f4* dv = (f4*)(dst + (size_t)p * NC);
#pragma unroll
    for (int i = 0; i < 4; ++i)
        dv[i] = make_float4(v[4 * i], v[4 * i + 1], v[4 * i + 2], v[4 * i + 3]);
}

// ---------------- gated residual layer: f=tanh(conv), g=sigmoid(conv), 1x1 ----
__global__ __launch_bounds__(256) void gated_k(
    const float* __restrict__ src, float* __restrict__ dst,
    const float* __restrict__ Wf, const float* __restrict__ bf,
    const float* __restrict__ Wg, const float* __restrict__ bg,
    const float* __restrict__ Wr, const float* __restrict__ br,
    int dil)
{
    const int p = blockIdx.x * 256 + threadIdx.x;
    const int n = p & (NN - 1);
    const float pad = (n >= dil) ? 1.0f : 0.0f;   // causal zero-pad
    const int pp = (n >= dil) ? (p - dil) : p;    // safe address

    float xc[NC], xp[NC];
    {
        const f4* a = (const f4*)(src + (size_t)p * NC);
        const f4* bq = (const f4*)(src + (size_t)pp * NC);
#pragma unroll
        for (int i = 0; i < 4; ++i) {
            f4 t = a[i];
            xc[4 * i + 0] = t.x; xc[4 * i + 1] = t.y;
            xc[4 * i + 2] = t.z; xc[4 * i + 3] = t.w;
            f4 u = bq[i];
            xp[4 * i + 0] = u.x * pad; xp[4 * i + 1] = u.y * pad;
            xp[4 * i + 2] = u.z * pad; xp[4 * i + 3] = u.w * pad;
        }
    }

    float z[NC];
#pragma unroll
    for (int o = 0; o < NC; ++o) {
        float af = bf[o];
        float ag = bg[o];
#pragma unroll
        for (int c = 0; c < NC; ++c) {
            const int w = (o * NC + c) * 2;
            af = fmaf(Wf[w], xp[c], af);
            af = fmaf(Wf[w + 1], xc[c], af);
            ag = fmaf(Wg[w], xp[c], ag);
            ag = fmaf(Wg[w + 1], xc[c], ag);
        }
        // tanh(af) = 1 - 2/(exp(2*af)+1)   (saturates correctly via inf)
        const float ef = __expf(2.0f * af);
        const float tf = 1.0f - 2.0f * __builtin_amdgcn_rcpf(ef + 1.0f);
        // sigmoid(ag) = 1/(1+exp(-ag))
        const float sg = __builtin_amdgcn_rcpf(1.0f + __expf(-ag));
        z[o] = tf * sg;
    }

#pragma unroll
    for (int o = 0; o < NC; ++o) {
        float acc = br[o];
#pragma unroll
        for (int c = 0; c < NC; ++c)
            acc = fmaf(Wr[o * NC + c], z[c], acc);
        xc[o] += acc;   // residual: inp += out
    }

    f4* dv = (f4*)(dst + (size_t)p * NC);
#pragma unroll
    for (int i = 0; i < 4; ++i)
        dv[i] = make_float4(xc[4 * i], xc[4 * i + 1], xc[4 * i + 2], xc[4 * i + 3]);
}

// ---------------- head: skip=relu(inp_final - xs), 16->64->256, log_softmax ---
__global__ __launch_bounds__(256) void head_k(
    const float* __restrict__ fin, const float* __restrict__ x,
    const int* __restrict__ lengths,
    const float* __restrict__ Wa, const float* __restrict__ ba,
    const float* __restrict__ Wo, const float* __restrict__ bo,
    float* __restrict__ out)
{
    const int p = blockIdx.x * 256 + threadIdx.x;
    const int n = p & (NN - 1);
    const int b = p >> 14;

    const float xs = x[p] * (1.0f / 32768.0f);

    float ra[64];
    {
        float sk[NC];
        const f4* a = (const f4*)(fin + (size_t)p * NC);
#pragma unroll
        for (int i = 0; i < 4; ++i) {
            f4 t = a[i];
            sk[4 * i + 0] = fmaxf(t.x - xs, 0.0f);
            sk[4 * i + 1] = fmaxf(t.y - xs, 0.0f);
            sk[4 * i + 2] = fmaxf(t.z - xs, 0.0f);
            sk[4 * i + 3] = fmaxf(t.w - xs, 0.0f);
        }
#pragma unroll
        for (int o = 0; o < 64; ++o) {
            float acc = ba[o];
#pragma unroll
            for (int c = 0; c < NC; ++c)
                acc = fmaf(Wa[o * NC + c], sk[c], acc);
            ra[o] = fmaxf(acc, 0.0f);   // relu(a)
        }
    }

    // pass 1: online logsumexp over 256 logits
    float m = -3.0e38f, s = 0.0f;
#pragma unroll 1
    for (int q = 0; q < 256; ++q) {
        float l = bo[q];
#pragma unroll
        for (int o = 0; o < 64; ++o)
            l = fmaf(Wo[q * 64 + o], ra[o], l);
        const float nm = fmaxf(m, l);
        s = s * __expf(m - nm) + __expf(l - nm);
        m = nm;
    }
    const float lse = m + __logf(s);
    const bool valid = n < lengths[b];

    // pass 2: recompute logits, write logp * mask
    float* ob = out + (size_t)b * 256 * NN + n;
#pragma unroll 1
    for (int q = 0; q < 256; ++q) {
        float l = bo[q];
#pragma unroll
        for (int o = 0; o < 64; ++o)
            l = fmaf(Wo[q * 64 + o], ra[o], l);
        ob[(size_t)q * NN] = valid ? (l - lse) : 0.0f;
    }
}

extern "C" void kernel_launch(void* const* d_in, const int* in_sizes, int n_in,
                              void* d_out, int out_size, void* d_ws, size_t ws_size,
                              hipStream_t stream)
{
    const float* x       = (const float*)d_in[0];
    const int*   lengths = (const int*)d_in[1];
    const float* W0      = (const float*)d_in[2];
    const float* b0      = (const float*)d_in[3];
    const float* Wf      = (const float*)d_in[4];
    const float* bf      = (const float*)d_in[5];
    const float* Wg      = (const float*)d_in[6];
    const float* bg      = (const float*)d_in[7];
    const float* Wr      = (const float*)d_in[8];
    const float* br      = (const float*)d_in[9];
    const float* Wa      = (const float*)d_in[10];
    const float* ba      = (const float*)d_in[11];
    const float* Wo      = (const float*)d_in[12];
    const float* bo      = (const float*)d_in[13];
    float* out = (float*)d_out;

    float* buf0 = (float*)d_ws;                    // (B,N,16) fp32, 8.4 MB
    float* buf1 = buf0 + (size_t)NPOSTOT * NC;     // second ping-pong buffer

    dim3 grid(NPOSTOT / 256), block(256);

    layer0_k<<<grid, block, 0, stream>>>(x, W0, b0, buf0);

    int cur = 0;
    for (int i = 1; i < 30; ++i) {
        const int j = i - 1;
        const int dil = 1 << (i % 10);
        const float* s = cur ? buf1 : buf0;
        float* d       = cur ? buf0 : buf1;
        gated_k<<<grid, block, 0, stream>>>(
            s, d,
            Wf + (size_t)j * NC * NC * 2, bf + (size_t)j * NC,
            Wg + (size_t)j * NC * NC * 2, bg + (size_t)j * NC,
            Wr + (size_t)j * NC * NC,     br + (size_t)j * NC,
            dil);
        cur ^= 1;
    }

    const float* fin = cur ? buf1 : buf0;   // cur == 1 after 29 layers
    head_k<<<grid, block, 0, stream>>>(fin, x, lengths, Wa, ba, Wo, bo, out);
}